// Round 6
// baseline (8480.737 us; speedup 1.0000x reference)
//
#include <hip/hip_runtime.h>
#include <stdint.h>

// ODE-LSTM (PersonActivityModel): B=256,T=128,IN=64,H=512,C=11, fp32 in/out.
//
// u-space RK4 folding: M = W2^T W1^T, d = b2·W1^T:
//   u1 = h·W1^T+b1; D_i = tanh(u_i)·M; u2=u1+.5dt(D1+d); u3=u1+.5dt(D2+d);
//   u4=u1+dt(D3+d); SM=D1+2D2+2D3+D4; u_next=u1+(dt/6)SM+dt·d;
//   S=t1+2t2+2t3+t4 over 3 unfolds; h += (dt/6)(S_tot·W2^T)+3dt·b2.
// out = h·(Wc·Wo)^T + (Wc·bo + bc) deferred; gates z = [h|x]·[Whh|Wih]^T.
//
// 16 clusters (16 batches) x 8 CUs (64-col slab), blockIdx = s*16+c so all 8
// slabs of a cluster share blockIdx%8 -> same XCD under round-robin (heuristic).
// ROUND-6: dual-path exchange. FAST (runtime-verified same-XCD via
// HW_REG_XCC_ID probe + global-mask sanity): data = plain stores -> XCD L2,
// volatile (sc0) loads; counter stays agent-scope memory-side (ordering point).
// SLOW fallback = round-5 agent atomics everywhere. Correctness is placement-
// independent; placement only selects speed. A-operands staged in fragment-
// layout LDS (AF) -> coalesced ds_read_b128, zero bank conflicts.

#define H_  512
#define B_  256
#define T_  128
#define IN_ 64
#define NC_ 11

typedef _Float16 h8v __attribute__((ext_vector_type(8)));
typedef float    f4v __attribute__((ext_vector_type(4)));
typedef unsigned long long ull;

__device__ __forceinline__ float fsigm(float x) { return 1.0f / (1.0f + __expf(-x)); }
__device__ __forceinline__ float ftanh(float x) { return 1.0f - 2.0f / (1.0f + __expf(2.0f * x)); }

// ---------------- prep kernels (fp32 weights -> fp16 MFMA B-fragment tables) ----------------

__global__ void prep_M(const float* __restrict__ W1, const float* __restrict__ W2,
                       float* __restrict__ Mtmp) {
  __shared__ float w1s[8][512];
  int tid = threadIdx.x;
  int n0 = blockIdx.x * 8;
  for (int i = tid; i < 8 * 512; i += 256) {
    int nn = i >> 9, m = i & 511;
    w1s[nn][m] = W1[(n0 + nn) * 512 + m];
  }
  __syncthreads();
  float acc0[8] = {0,0,0,0,0,0,0,0}, acc1[8] = {0,0,0,0,0,0,0,0};
  for (int m = 0; m < 512; ++m) {
    float a = W2[m * 512 + tid];
    float b = W2[m * 512 + 256 + tid];
#pragma unroll
    for (int j = 0; j < 8; ++j) { acc0[j] += a * w1s[j][m]; acc1[j] += b * w1s[j][m]; }
  }
  for (int j = 0; j < 8; ++j) {
    Mtmp[(size_t)tid * 512 + n0 + j]         = acc0[j];
    Mtmp[(size_t)(tid + 256) * 512 + n0 + j] = acc1[j];
  }
}

__global__ void prep_small(const float* __restrict__ W1, const float* __restrict__ b2,
                           const float* __restrict__ Wc, const float* __restrict__ Wo,
                           const float* __restrict__ bo, const float* __restrict__ bc,
                           float* __restrict__ dvec, float* __restrict__ Wco,
                           float* __restrict__ bprime) {
  __shared__ float wcs[NC_ * 512];
  int tid = threadIdx.x;
  if (blockIdx.x == 0) {
    for (int n = tid; n < 512; n += 256) {
      float acc = 0.f;
      for (int m = 0; m < 512; ++m) acc += b2[m] * W1[n * 512 + m];
      dvec[n] = acc;
    }
  } else if (blockIdx.x == 1) {
    if (tid < NC_) {
      float acc = bc[tid];
      for (int m = 0; m < 512; ++m) acc += Wc[tid * 512 + m] * bo[m];
      bprime[tid] = acc;
    }
  } else {
    for (int i = tid; i < NC_ * 512; i += 256) wcs[i] = Wc[i];
    __syncthreads();
    int h = (blockIdx.x - 2) * 256 + tid;
    float acc[NC_];
#pragma unroll
    for (int c = 0; c < NC_; ++c) acc[c] = 0.f;
    for (int m = 0; m < 512; ++m) {
      float wo = Wo[m * 512 + h];
#pragma unroll
      for (int c = 0; c < NC_; ++c) acc[c] += wo * wcs[c * 512 + m];
    }
    for (int c = 0; c < NC_; ++c) Wco[c * 512 + h] = acc[c];
  }
}

// B-frag tables: frag fb = 64 lanes x 8 halfs (1KB). B[k][n]:
// lane holds n = tile*16+(lane&15), k = kc*32+((lane>>4)&3)*8+j.
__global__ void prep_wtilde(const float* __restrict__ Whh, const float* __restrict__ Wih,
                            _Float16* __restrict__ Wtil) {
  int gidx = blockIdx.x * 256 + threadIdx.x;  // 2304 fb * 64 lanes
  int lane = gidx & 63, fb = gidx >> 6;
  int kc = fb % 18; int t2 = fb / 18;
  int t = t2 & 31, g = t2 >> 5;
  int n = g * 512 + t * 16 + (lane & 15);
  int k = kc * 32 + ((lane >> 4) & 3) * 8;
  _Float16 vals[8];
  if (k < 512) {
#pragma unroll
    for (int j = 0; j < 8; ++j) vals[j] = (_Float16)Whh[(size_t)n * 512 + k + j];
  } else {
#pragma unroll
    for (int j = 0; j < 8; ++j) vals[j] = (_Float16)Wih[(size_t)n * 64 + (k - 512) + j];
  }
  *(h8v*)(Wtil + (size_t)fb * 512 + lane * 8) = *(h8v*)vals;
}

__global__ void prep_fragW(const float* __restrict__ W, _Float16* __restrict__ dst) {
  int gidx = blockIdx.x * 256 + threadIdx.x;  // 512 fb * 64 lanes
  int lane = gidx & 63, fb = gidx >> 6;
  int t = fb >> 4, kc = fb & 15;
  int n = t * 16 + (lane & 15);
  int k = kc * 32 + ((lane >> 4) & 3) * 8;
  _Float16 vals[8];
#pragma unroll
  for (int j = 0; j < 8; ++j) vals[j] = (_Float16)W[(size_t)n * 512 + k + j];
  *(h8v*)(dst + (size_t)fb * 512 + lane * 8) = *(h8v*)vals;
}

__global__ void prep_fragM(const float* __restrict__ Mtmp, _Float16* __restrict__ dst) {
  int gidx = blockIdx.x * 256 + threadIdx.x;
  int lane = gidx & 63, fb = gidx >> 6;
  int t = fb >> 4, kc = fb & 15;
  int n = t * 16 + (lane & 15);
  int k = kc * 32 + ((lane >> 4) & 3) * 8;
  _Float16 vals[8];
#pragma unroll
  for (int j = 0; j < 8; ++j) vals[j] = (_Float16)Mtmp[(size_t)(k + j) * 512 + n];
  *(h8v*)(dst + (size_t)fb * 512 + lane * 8) = *(h8v*)vals;
}

// ---------------- recurrence ----------------

// AF fragment layout: AF[kc*512 + lane*8 + j] = act[m = lane&15][col = kc*32 + (lane>>4)*8 + j].
// Position of act[m][col]: (col>>5)*512 + (m + ((col>>3)&3)*16)*8 + (col&7).
__device__ __forceinline__ int af_idx(int m, int col) {
  return (col >> 5) * 512 + ((m & 15) + ((col >> 3) & 3) * 16) * 8 + (col & 7);
}

// Exchange: publish own 64-col slab (already in AF) as 256 8B words, barrier on
// agent-scope counter, gather all 2048 words back into AF.
// Xb word (m, c0=os*64+ch*4) at m*128 + os*16 + ch, 4 halfs = cols c0..c0+3.
__device__ __forceinline__ void phase_exchange(bool fast, int* __restrict__ cnt,
                                               ull* __restrict__ Xb,
                                               _Float16* __restrict__ AF,
                                               int s, int target) {
  const int tid = threadIdx.x;
  __syncthreads();                                   // AF epilogue writes done
  {
    int m = tid >> 4, ch = tid & 15;
    int c0 = s * 64 + ch * 4;
    const uint32_t* src = (const uint32_t*)(AF + af_idx(m, c0));
    ull v = ((ull)src[1] << 32) | (ull)src[0];
    ull* dst = Xb + m * 128 + s * 16 + ch;
    if (fast) *(volatile ull*)dst = v;               // XCD-L2 resident
    else __hip_atomic_store(dst, v, __ATOMIC_RELAXED, __HIP_MEMORY_SCOPE_AGENT);
  }
  __builtin_amdgcn_s_waitcnt(0);                     // data committed (L2 / LLC)
  __syncthreads();
  if (tid == 0) {                                    // single-thread arrive+poll
    __hip_atomic_fetch_add(cnt, 1, __ATOMIC_RELAXED, __HIP_MEMORY_SCOPE_AGENT);
    int v;
    do {
      v = __hip_atomic_load(cnt, __ATOMIC_RELAXED, __HIP_MEMORY_SCOPE_AGENT);
      if (v < target) __builtin_amdgcn_s_sleep(1);
    } while (v < target);
  }
  __syncthreads();                                   // release all waves
  ull tv[8];
  if (fast) {
#pragma unroll
    for (int i = 0; i < 8; ++i) {
      int idx = i * 256 + tid, os = idx >> 8, r = idx & 255, m = r >> 4, ch = r & 15;
      tv[i] = *(volatile const ull*)(Xb + m * 128 + os * 16 + ch);  // sc0: bypass L1, hit XCD L2
    }
  } else {
#pragma unroll
    for (int i = 0; i < 8; ++i) {
      int idx = i * 256 + tid, os = idx >> 8, r = idx & 255, m = r >> 4, ch = r & 15;
      tv[i] = __hip_atomic_load(Xb + m * 128 + os * 16 + ch,
                                __ATOMIC_RELAXED, __HIP_MEMORY_SCOPE_AGENT);
    }
  }
#pragma unroll
  for (int i = 0; i < 8; ++i) {
    int idx = i * 256 + tid, os = idx >> 8, r = idx & 255, m = r >> 4, ch = r & 15;
    int c0 = os * 64 + ch * 4;
    uint32_t* d = (uint32_t*)(AF + af_idx(m, c0));
    d[0] = (uint32_t)tv[i]; d[1] = (uint32_t)(tv[i] >> 32);
  }
  __syncthreads();                                   // AF fully staged
}

// One 16x512 @ 512x64 slab phase; A from AF (coalesced b128), B from LDS table.
__device__ __forceinline__ f4v mm_lds(const _Float16* __restrict__ AF,
                                      const _Float16* __restrict__ Ws,
                                      int w, int lane) {
  f4v e = {0,0,0,0}, o = {0,0,0,0};
  const h8v* a = (const h8v*)AF;
  const h8v* b = (const h8v*)Ws;
#pragma unroll
  for (int kc = 0; kc < 16; kc += 2) {
    e = __builtin_amdgcn_mfma_f32_16x16x32_f16(a[kc * 64 + lane],
                                               b[(w * 16 + kc) * 64 + lane], e, 0, 0, 0);
    o = __builtin_amdgcn_mfma_f32_16x16x32_f16(a[(kc + 1) * 64 + lane],
                                               b[(w * 16 + kc + 1) * 64 + lane], o, 0, 0, 0);
  }
  return e + o;
}

__device__ __forceinline__ f4v mm_reg(const _Float16* __restrict__ AF,
                                      const h8v* __restrict__ mreg, int lane) {
  f4v e = {0,0,0,0}, o = {0,0,0,0};
  const h8v* a = (const h8v*)AF;
#pragma unroll
  for (int kc = 0; kc < 16; kc += 2) {
    e = __builtin_amdgcn_mfma_f32_16x16x32_f16(a[kc * 64 + lane], mreg[kc], e, 0, 0, 0);
    o = __builtin_amdgcn_mfma_f32_16x16x32_f16(a[(kc + 1) * 64 + lane], mreg[kc + 1], o, 0, 0, 0);
  }
  return e + o;
}

__launch_bounds__(256, 1)
__global__ void recur(const float* __restrict__ x,
                      const float* __restrict__ tin,
                      const float* __restrict__ bih,
                      const float* __restrict__ bhh,
                      const float* __restrict__ b1g,
                      const float* __restrict__ b2g,
                      const _Float16* __restrict__ Wtil,
                      const _Float16* __restrict__ W1T,
                      const _Float16* __restrict__ W2T,
                      const _Float16* __restrict__ MF,
                      const float* __restrict__ dvec,
                      _Float16* __restrict__ Hsave,
                      ull* __restrict__ Xchg,
                      int* __restrict__ flags) {
  const int blk = blockIdx.x, c = blk & 15, s = blk >> 4;   // cluster, slab
  const int tid = threadIdx.x, w = tid >> 6, lane = tid & 63;
  const int lm = lane & 15, quad = lane >> 4;
  const int col = s * 64 + w * 16 + lm;                     // global hidden col

  __shared__ __align__(16) _Float16 W1s[4 * 16 * 512];      // 64 KB
  __shared__ __align__(16) _Float16 W2s[4 * 16 * 512];      // 64 KB
  __shared__ __align__(16) _Float16 AF[16 * 512];           // 16 KB frag layout
  __shared__ int fastsh;

  {
    const h8v* g1 = (const h8v*)(W1T + (size_t)s * 32768);
    const h8v* g2 = (const h8v*)(W2T + (size_t)s * 32768);
    h8v* l1 = (h8v*)W1s; h8v* l2 = (h8v*)W2s;
    for (int i = tid; i < 4096; i += 256) { l1[i] = g1[i]; l2[i] = g2[i]; }
  }
  h8v mreg[16];
  {
    const h8v* gm = (const h8v*)(MF + ((size_t)(4 * s + w) * 16) * 512);
#pragma unroll
    for (int kc = 0; kc < 16; ++kc) mreg[kc] = gm[kc * 64 + lane];
  }
  for (int i = tid; i < 1024; i += 256) ((uint4*)AF)[i] = make_uint4(0, 0, 0, 0);

  // ---- placement probe: fast path iff all 8 slabs share one XCC and the grid
  // saw >=2 distinct XCCs (guards a misdecoded register). One-time cost. ----
  {
    int xcc = 0;
    __asm__ volatile("s_getreg_b32 %0, hwreg(HW_REG_XCC_ID)" : "=s"(xcc));
    int* probes = flags + 512;          // [16][8]
    int* pgcnt  = flags + 512 + 128;
    int* pmask  = flags + 512 + 129;
    if (tid == 0) {
      __hip_atomic_store(&probes[c * 8 + s], xcc, __ATOMIC_RELAXED, __HIP_MEMORY_SCOPE_AGENT);
      __hip_atomic_fetch_or(pmask, 1 << (xcc & 31), __ATOMIC_RELAXED, __HIP_MEMORY_SCOPE_AGENT);
      __builtin_amdgcn_s_waitcnt(0);
      __hip_atomic_fetch_add(pgcnt, 1, __ATOMIC_RELAXED, __HIP_MEMORY_SCOPE_AGENT);
      while (__hip_atomic_load(pgcnt, __ATOMIC_RELAXED, __HIP_MEMORY_SCOPE_AGENT) < 128)
        __builtin_amdgcn_s_sleep(4);
      int e0 = __hip_atomic_load(&probes[c * 8], __ATOMIC_RELAXED, __HIP_MEMORY_SCOPE_AGENT);
      int eq = 1;
      for (int i = 1; i < 8; ++i)
        eq &= (__hip_atomic_load(&probes[c * 8 + i], __ATOMIC_RELAXED, __HIP_MEMORY_SCOPE_AGENT) == e0);
      int mk = __hip_atomic_load(pmask, __ATOMIC_RELAXED, __HIP_MEMORY_SCOPE_AGENT);
      fastsh = (eq && __popc((unsigned)mk) >= 2) ? 1 : 0;
    }
  }
  __syncthreads();
  const bool fast = (fastsh != 0);

  const float zb0 = bih[col] + bhh[col];
  const float zb1 = bih[512 + col] + bhh[512 + col];
  const float zb2 = bih[1024 + col] + bhh[1024 + col];
  const float zb3 = bih[1536 + col] + bhh[1536 + col];
  const float b1r = b1g[col], dvr = dvec[col], b2r = b2g[col];
  const int eb = af_idx(quad * 4, col);              // epilogue base; +r*8 per r

  float c_[4] = {0,0,0,0}, h_[4] = {0,0,0,0};
  float u1a[4], SSa[4], SMa[4];
  int phase = 0;
  int* cnt = flags + c * 32;
  __syncthreads();

  for (int ts = 0; ts < T_; ++ts) {
    float dt_[4];
#pragma unroll
    for (int r = 0; r < 4; ++r)
      dt_[r] = tin[(c * 16 + quad * 4 + r) * T_ + ts] * (1.0f / 3.0f);

    // ---- P1: gates z = [h|x]·Wtil^T (K=576; B streamed from L2) ----
    {
      f4v z0 = {0,0,0,0}, z1 = {0,0,0,0}, z2 = {0,0,0,0}, z3 = {0,0,0,0};
      const h8v* a = (const h8v*)AF;
      const h8v* wt = (const h8v*)Wtil;
      const int tb = 4 * s + w;
#pragma unroll
      for (int kc = 0; kc < 16; ++kc) {
        h8v av = a[kc * 64 + lane];
        z0 = __builtin_amdgcn_mfma_f32_16x16x32_f16(av, wt[(size_t)((0 * 32 + tb) * 18 + kc) * 64 + lane], z0, 0, 0, 0);
        z1 = __builtin_amdgcn_mfma_f32_16x16x32_f16(av, wt[(size_t)((1 * 32 + tb) * 18 + kc) * 64 + lane], z1, 0, 0, 0);
        z2 = __builtin_amdgcn_mfma_f32_16x16x32_f16(av, wt[(size_t)((2 * 32 + tb) * 18 + kc) * 64 + lane], z2, 0, 0, 0);
        z3 = __builtin_amdgcn_mfma_f32_16x16x32_f16(av, wt[(size_t)((3 * 32 + tb) * 18 + kc) * 64 + lane], z3, 0, 0, 0);
      }
      const float* xr = x + ((size_t)(c * 16 + lm) * T_ + ts) * IN_ + quad * 8;
#pragma unroll
      for (int kx = 0; kx < 2; ++kx) {
        float4 f0 = *(const float4*)(xr + kx * 32);
        float4 f1 = *(const float4*)(xr + kx * 32 + 4);
        h8v av;
        av[0] = (_Float16)f0.x; av[1] = (_Float16)f0.y; av[2] = (_Float16)f0.z; av[3] = (_Float16)f0.w;
        av[4] = (_Float16)f1.x; av[5] = (_Float16)f1.y; av[6] = (_Float16)f1.z; av[7] = (_Float16)f1.w;
        int kc = 16 + kx;
        z0 = __builtin_amdgcn_mfma_f32_16x16x32_f16(av, wt[(size_t)((0 * 32 + tb) * 18 + kc) * 64 + lane], z0, 0, 0, 0);
        z1 = __builtin_amdgcn_mfma_f32_16x16x32_f16(av, wt[(size_t)((1 * 32 + tb) * 18 + kc) * 64 + lane], z1, 0, 0, 0);
        z2 = __builtin_amdgcn_mfma_f32_16x16x32_f16(av, wt[(size_t)((2 * 32 + tb) * 18 + kc) * 64 + lane], z2, 0, 0, 0);
        z3 = __builtin_amdgcn_mfma_f32_16x16x32_f16(av, wt[(size_t)((3 * 32 + tb) * 18 + kc) * 64 + lane], z3, 0, 0, 0);
      }
      __syncthreads();                    // all waves done reading AF (h_prev)
#pragma unroll
      for (int r = 0; r < 4; ++r) {
        float zi = z0[r] + zb0, zf = z1[r] + zb1, zg = z2[r] + zb2, zo = z3[r] + zb3;
        float cv = fsigm(zf) * c_[r] + fsigm(zi) * ftanh(zg);
        c_[r] = cv;
        h_[r] = fsigm(zo) * ftanh(cv);
        AF[eb + r * 8] = (_Float16)h_[r];
      }
    }
    ++phase;
    phase_exchange(fast, cnt, Xchg + (size_t)((phase & 1) * 16 + c) * 2048, AF, s, 8 * phase);

    // ---- P2: u1 = h·W1^T + b1 ----
    {
      f4v D = mm_lds(AF, W1s, w, lane);
      __syncthreads();
#pragma unroll
      for (int r = 0; r < 4; ++r) {
        float uv = D[r] + b1r;
        u1a[r] = uv;
        float t1v = ftanh(uv);
        SSa[r] = t1v;
        AF[eb + r * 8] = (_Float16)t1v;
      }
    }
    ++phase;
    phase_exchange(fast, cnt, Xchg + (size_t)((phase & 1) * 16 + c) * 2048, AF, s, 8 * phase);

    // ---- 3 RK4 unfolds in u-space (M in VGPRs) ----
#pragma unroll 1
    for (int uf = 0; uf < 3; ++uf) {
      {
        f4v D = mm_reg(AF, mreg, lane);
        __syncthreads();
#pragma unroll
        for (int r = 0; r < 4; ++r) {
          float Dv = D[r];
          float u2 = u1a[r] + 0.5f * dt_[r] * (Dv + dvr);
          SMa[r] = Dv;
          float t2v = ftanh(u2);
          SSa[r] += 2.0f * t2v;
          AF[eb + r * 8] = (_Float16)t2v;
        }
      }
      ++phase;
      phase_exchange(fast, cnt, Xchg + (size_t)((phase & 1) * 16 + c) * 2048, AF, s, 8 * phase);

      {
        f4v D = mm_reg(AF, mreg, lane);
        __syncthreads();
#pragma unroll
        for (int r = 0; r < 4; ++r) {
          float Dv = D[r];
          float u3 = u1a[r] + 0.5f * dt_[r] * (Dv + dvr);
          SMa[r] += 2.0f * Dv;
          float t3v = ftanh(u3);
          SSa[r] += 2.0f * t3v;
          AF[eb + r * 8] = (_Float16)t3v;
        }
      }
      ++phase;
      phase_exchange(fast, cnt, Xchg + (size_t)((phase & 1) * 16 + c) * 2048, AF, s, 8 * phase);

      {
        f4v D = mm_reg(AF, mreg, lane);
        __syncthreads();
#pragma unroll
        for (int r = 0; r < 4; ++r) {
          float Dv = D[r];
          float u4 = u1a[r] + dt_[r] * (Dv + dvr);
          SMa[r] += 2.0f * Dv;
          float t4v = ftanh(u4);
          SSa[r] += t4v;
          AF[eb + r * 8] = (uf < 2) ? (_Float16)t4v : (_Float16)SSa[r];
        }
      }
      ++phase;
      phase_exchange(fast, cnt, Xchg + (size_t)((phase & 1) * 16 + c) * 2048, AF, s, 8 * phase);

      if (uf < 2) {
        f4v D = mm_reg(AF, mreg, lane);
        __syncthreads();
#pragma unroll
        for (int r = 0; r < 4; ++r) {
          float Dv = D[r];
          SMa[r] += Dv;
          float un = u1a[r] + (dt_[r] * (1.0f / 6.0f)) * SMa[r] + dt_[r] * dvr;
          u1a[r] = un;
          float t1v = ftanh(un);
          SSa[r] += t1v;
          AF[eb + r * 8] = (_Float16)t1v;
        }
        ++phase;
        phase_exchange(fast, cnt, Xchg + (size_t)((phase & 1) * 16 + c) * 2048, AF, s, 8 * phase);
      }
    }

    // ---- P_h: h += (dt/6)·(S_tot·W2^T) + 3dt·b2 ; publish h + Hsave ----
    {
      f4v D = mm_lds(AF, W2s, w, lane);
      __syncthreads();
#pragma unroll
      for (int r = 0; r < 4; ++r) {
        h_[r] += (dt_[r] * (1.0f / 6.0f)) * D[r] + (3.0f * dt_[r]) * b2r;
        _Float16 hv = (_Float16)h_[r];
        AF[eb + r * 8] = hv;
        Hsave[((size_t)(ts + 1) * B_ + c * 16 + quad * 4 + r) * H_ + col] = hv;
      }
    }
    ++phase;
    phase_exchange(fast, cnt, Xchg + (size_t)((phase & 1) * 16 + c) * 2048, AF, s, 8 * phase);
  }
}

// ---------------- final projection: out = h·Wco^T + bprime ----------------
__global__ void final_out(const _Float16* __restrict__ Hsave,
                          const float* __restrict__ Wco,
                          const float* __restrict__ bprime,
                          float* __restrict__ out) {
  __shared__ float wcs[NC_][520];
  int tid = threadIdx.x;
  for (int i = tid; i < NC_ * 512; i += 256) wcs[i >> 9][i & 511] = Wco[i];
  __syncthreads();
  int r0 = blockIdx.x * 64;
  int rl = tid >> 4, cc = tid & 15;
  for (int pass = 0; pass < 4; ++pass) {
    int row = r0 + pass * 16 + rl;        // row = b*T + t
    int b = row >> 7, t = row & 127;
    const _Float16* hrow = Hsave + ((size_t)(t + 1) * B_ + b) * H_;
    if (cc < NC_) {
      float acc = 0.f;
      for (int k8 = 0; k8 < 64; ++k8) {
        h8v hv = *(const h8v*)(hrow + k8 * 8);
#pragma unroll
        for (int j = 0; j < 8; ++j) acc += (float)hv[j] * wcs[cc][k8 * 8 + j];
      }
      out[(size_t)row * NC_ + cc] = acc + bprime[cc];
    }
  }
}

extern "C" void kernel_launch(void* const* d_in, const int* in_sizes, int n_in,
                              void* d_out, int out_size, void* d_ws, size_t ws_size,
                              hipStream_t stream) {
  (void)in_sizes; (void)n_in; (void)out_size; (void)ws_size;
  const float* x   = (const float*)d_in[0];
  const float* tin = (const float*)d_in[1];
  const float* Wih = (const float*)d_in[2];
  const float* Whh = (const float*)d_in[3];
  const float* bih = (const float*)d_in[4];
  const float* bhh = (const float*)d_in[5];
  const float* W1  = (const float*)d_in[6];
  const float* b1  = (const float*)d_in[7];
  const float* W2  = (const float*)d_in[8];
  const float* b2  = (const float*)d_in[9];
  const float* Wo  = (const float*)d_in[10];
  const float* bo  = (const float*)d_in[11];
  const float* Wc  = (const float*)d_in[12];
  const float* bc  = (const float*)d_in[13];

  char* ws = (char*)d_ws;
  size_t off = 0;
  auto alloc = [&](size_t bytes) -> void* {
    void* p = ws + off;
    off = (off + bytes + 1023) & ~(size_t)1023;
    return p;
  };
  _Float16* Wtil  = (_Float16*)alloc((size_t)2304 * 512 * 2);
  _Float16* W1T   = (_Float16*)alloc((size_t)512 * 512 * 2);
  _Float16* W2T   = (_Float16*)alloc((size_t)512 * 512 * 2);
  _Float16* MF    = (_Float16*)alloc((size_t)512 * 512 * 2);
  float*    Mtmp  = (float*)alloc((size_t)512 * 512 * 4);
  float*    dvec  = (float*)alloc(512 * 4);
  float*    WcoF  = (float*)alloc((size_t)NC_ * 512 * 4);
  float*    bprim = (float*)alloc(64);
  _Float16* Hsave = (_Float16*)alloc((size_t)(T_ + 1) * B_ * H_ * 2);
  ull*      Xchg  = (ull*)alloc((size_t)2 * 16 * 2048 * 8);
  int*      flags = (int*)alloc((512 + 192) * 4);

  hipMemsetAsync(flags, 0, (512 + 192) * 4, stream);

  prep_M<<<64, 256, 0, stream>>>(W1, W2, Mtmp);
  prep_small<<<4, 256, 0, stream>>>(W1, b2, Wc, Wo, bo, bc, dvec, WcoF, bprim);
  prep_wtilde<<<576, 256, 0, stream>>>(Whh, Wih, Wtil);
  prep_fragW<<<128, 256, 0, stream>>>(W1, W1T);
  prep_fragW<<<128, 256, 0, stream>>>(W2, W2T);
  prep_fragM<<<128, 256, 0, stream>>>(Mtmp, MF);
  recur<<<128, 256, 0, stream>>>(x, tin, bih, bhh, b1, b2, Wtil, W1T, W2T, MF,
                                 dvec, Hsave, Xchg, flags);
  final_out<<<512, 256, 0, stream>>>(Hsave, WcoF, bprim, (float*)d_out);
}

// Round 10
// 8404.961 us; speedup vs baseline: 1.0090x; 1.0090x over previous
//
#include <hip/hip_runtime.h>
#include <stdint.h>

// ODE-LSTM (PersonActivityModel): B=256,T=128,IN=64,H=512,C=11, fp32 in/out.
//
// u-space RK4 folding: M = W2^T W1^T, d = b2·W1^T:
//   u1 = h·W1^T+b1; D_i = tanh(u_i)·M; u2=u1+.5dt(D1+d); u3=u1+.5dt(D2+d);
//   u4=u1+dt(D3+d); SM=D1+2D2+2D3+D4; u_next=u1+(dt/6)SM+dt·d;
//   S=t1+2t2+2t3+t4 over 3 unfolds; h += (dt/6)(S_tot·W2^T)+3dt·b2.
// out = h·(Wc·Wo)^T + (Wc·bo + bc) deferred; gates z = [h|x]·[Whh|Wih]^T.
//
// ROUND-10: cluster-pair latency hiding with ONLY round-5-proven primitives.
// 64 WGs: blk = s*8 + j -> slab s of clusters A=2j, B=2j+1 (16 batches each).
// Phases interleave A,B: while A's exchange round-trips the LLC, the WG
// computes B's phase. Exchange protocol = round 5 exactly (relaxed AGENT-scope
// atomics for data + monotonic counters; depth-2 ping-pong; publish p+1 only
// after gathering p). Changes vs r5: poll by tid0 only (kills LLC hammering),
// poll deferred to the start of the next phase (the hiding). No inline-asm
// memory ops, no sc-flag games, no XCD assumptions (r7/r9 hang class removed).
// Per CU: M-slab AND W2-slab B-frags in VGPRs (2x16 frags), W1 slab in LDS,
// gates table streamed from L2. LDS = 64KB (W1) + 2x16.25KB (ACT A/B).

#define H_  512
#define B_  256
#define T_  128
#define IN_ 64
#define NC_ 11
#define LD_ 520   // padded LDS row stride (halfs)

typedef _Float16 h8v __attribute__((ext_vector_type(8)));
typedef float    f4v __attribute__((ext_vector_type(4)));
typedef unsigned long long ull;

__device__ __forceinline__ float fsigm(float x) { return 1.0f / (1.0f + __expf(-x)); }
__device__ __forceinline__ float ftanh(float x) { return 1.0f - 2.0f / (1.0f + __expf(2.0f * x)); }

// ---------------- prep kernels (fp32 weights -> fp16 MFMA B-fragment tables) ----------------

__global__ void prep_M(const float* __restrict__ W1, const float* __restrict__ W2,
                       float* __restrict__ Mtmp) {
  __shared__ float w1s[8][512];
  int tid = threadIdx.x;
  int n0 = blockIdx.x * 8;
  for (int i = tid; i < 8 * 512; i += 256) {
    int nn = i >> 9, m = i & 511;
    w1s[nn][m] = W1[(n0 + nn) * 512 + m];
  }
  __syncthreads();
  float acc0[8] = {0,0,0,0,0,0,0,0}, acc1[8] = {0,0,0,0,0,0,0,0};
  for (int m = 0; m < 512; ++m) {
    float a = W2[m * 512 + tid];
    float b = W2[m * 512 + 256 + tid];
#pragma unroll
    for (int j = 0; j < 8; ++j) { acc0[j] += a * w1s[j][m]; acc1[j] += b * w1s[j][m]; }
  }
  for (int j = 0; j < 8; ++j) {
    Mtmp[(size_t)tid * 512 + n0 + j]         = acc0[j];
    Mtmp[(size_t)(tid + 256) * 512 + n0 + j] = acc1[j];
  }
}

__global__ void prep_small(const float* __restrict__ W1, const float* __restrict__ b2,
                           const float* __restrict__ Wc, const float* __restrict__ Wo,
                           const float* __restrict__ bo, const float* __restrict__ bc,
                           float* __restrict__ dvec, float* __restrict__ Wco,
                           float* __restrict__ bprime) {
  __shared__ float wcs[NC_ * 512];
  int tid = threadIdx.x;
  if (blockIdx.x == 0) {
    for (int n = tid; n < 512; n += 256) {
      float acc = 0.f;
      for (int m = 0; m < 512; ++m) acc += b2[m] * W1[n * 512 + m];
      dvec[n] = acc;
    }
  } else if (blockIdx.x == 1) {
    if (tid < NC_) {
      float acc = bc[tid];
      for (int m = 0; m < 512; ++m) acc += Wc[tid * 512 + m] * bo[m];
      bprime[tid] = acc;
    }
  } else {
    for (int i = tid; i < NC_ * 512; i += 256) wcs[i] = Wc[i];
    __syncthreads();
    int h = (blockIdx.x - 2) * 256 + tid;
    float acc[NC_];
#pragma unroll
    for (int c = 0; c < NC_; ++c) acc[c] = 0.f;
    for (int m = 0; m < 512; ++m) {
      float wo = Wo[m * 512 + h];
#pragma unroll
      for (int c = 0; c < NC_; ++c) acc[c] += wo * wcs[c * 512 + m];
    }
    for (int c = 0; c < NC_; ++c) Wco[c * 512 + h] = acc[c];
  }
}

// B-frag tables: frag fb = 64 lanes x 8 halfs (1KB). B[k][n]:
// lane holds n = tile*16+(lane&15), k = kc*32+((lane>>4)&3)*8+j.
__global__ void prep_wtilde(const float* __restrict__ Whh, const float* __restrict__ Wih,
                            _Float16* __restrict__ Wtil) {
  int gidx = blockIdx.x * 256 + threadIdx.x;  // 2304 fb * 64 lanes
  int lane = gidx & 63, fb = gidx >> 6;
  int kc = fb % 18; int t2 = fb / 18;
  int t = t2 & 31, g = t2 >> 5;
  int n = g * 512 + t * 16 + (lane & 15);
  int k = kc * 32 + ((lane >> 4) & 3) * 8;
  _Float16 vals[8];
  if (k < 512) {
#pragma unroll
    for (int j = 0; j < 8; ++j) vals[j] = (_Float16)Whh[(size_t)n * 512 + k + j];
  } else {
#pragma unroll
    for (int j = 0; j < 8; ++j) vals[j] = (_Float16)Wih[(size_t)n * 64 + (k - 512) + j];
  }
  *(h8v*)(Wtil + (size_t)fb * 512 + lane * 8) = *(h8v*)vals;
}

__global__ void prep_fragW(const float* __restrict__ W, _Float16* __restrict__ dst) {
  int gidx = blockIdx.x * 256 + threadIdx.x;  // 512 fb * 64 lanes
  int lane = gidx & 63, fb = gidx >> 6;
  int t = fb >> 4, kc = fb & 15;
  int n = t * 16 + (lane & 15);
  int k = kc * 32 + ((lane >> 4) & 3) * 8;
  _Float16 vals[8];
#pragma unroll
  for (int j = 0; j < 8; ++j) vals[j] = (_Float16)W[(size_t)n * 512 + k + j];
  *(h8v*)(dst + (size_t)fb * 512 + lane * 8) = *(h8v*)vals;
}

__global__ void prep_fragM(const float* __restrict__ Mtmp, _Float16* __restrict__ dst) {
  int gidx = blockIdx.x * 256 + threadIdx.x;
  int lane = gidx & 63, fb = gidx >> 6;
  int t = fb >> 4, kc = fb & 15;
  int n = t * 16 + (lane & 15);
  int k = kc * 32 + ((lane >> 4) & 3) * 8;
  _Float16 vals[8];
#pragma unroll
  for (int j = 0; j < 8; ++j) vals[j] = (_Float16)Mtmp[(size_t)(k + j) * 512 + n];
  *(h8v*)(dst + (size_t)fb * 512 + lane * 8) = *(h8v*)vals;
}

// ---------------- recurrence ----------------

// Gather phase `ph` of cluster c into ACT (skip peers' data if ph==0).
// Poll by tid0 only; data via relaxed agent-scope atomics (round-5 protocol).
__device__ __forceinline__ void gatherX(ull* __restrict__ Xchg, int c,
                                        int* __restrict__ cnt,
                                        _Float16* __restrict__ ACT,
                                        int s, int tid, unsigned ph) {
  if (ph == 0) return;
  if (tid == 0) {
    int target = 8 * (int)ph;
    while (__hip_atomic_load(cnt, __ATOMIC_RELAXED, __HIP_MEMORY_SCOPE_AGENT) < target)
      __builtin_amdgcn_s_sleep(1);
  }
  __syncthreads();
  ull* Xb = Xchg + (size_t)((ph & 1) * 16 + c) * 2048;
  const int m = tid >> 4, ch = tid & 15;
  ull tv[8];
#pragma unroll
  for (int i = 0; i < 8; ++i)
    tv[i] = __hip_atomic_load(Xb + m * 128 + i * 16 + ch,
                              __ATOMIC_RELAXED, __HIP_MEMORY_SCOPE_AGENT);
#pragma unroll
  for (int i = 0; i < 8; ++i)
    if (i != s)
      *(ull*)(ACT + m * LD_ + i * 64 + ch * 4) = tv[i];
  __syncthreads();
}

// Publish our slab's 64 cols of phase `phNew` (epilogue already wrote ACT).
__device__ __forceinline__ void publishX(ull* __restrict__ Xchg, int c,
                                         int* __restrict__ cnt,
                                         const _Float16* __restrict__ ACT,
                                         int s, int tid, unsigned phNew) {
  __syncthreads();                                   // epilogue ACT writes done
  ull* Xb = Xchg + (size_t)((phNew & 1) * 16 + c) * 2048;
  const int m = tid >> 4, ch = tid & 15;
  ull v = *(const ull*)(ACT + m * LD_ + s * 64 + ch * 4);
  __hip_atomic_store(Xb + m * 128 + s * 16 + ch, v,
                     __ATOMIC_RELAXED, __HIP_MEMORY_SCOPE_AGENT);
  __builtin_amdgcn_s_waitcnt(0);                     // data committed at LLC
  __syncthreads();                                   // all 256 threads done
  if (tid == 0)
    __hip_atomic_fetch_add(cnt, 1, __ATOMIC_RELAXED, __HIP_MEMORY_SCOPE_AGENT);
}

// One 16x512 @ 512x64 slab matmul. A: LDS row-major ACT (stride LD_).
__device__ __forceinline__ f4v mm_lds(const _Float16* __restrict__ ACT,
                                      const _Float16* __restrict__ Ws,
                                      int w, int lane) {
  f4v e = {0,0,0,0}, o = {0,0,0,0};
  const _Float16* arow = ACT + (lane & 15) * LD_ + (lane >> 4) * 8;
  const h8v* b = (const h8v*)Ws;
#pragma unroll
  for (int kc = 0; kc < 16; kc += 2) {
    e = __builtin_amdgcn_mfma_f32_16x16x32_f16(*(const h8v*)(arow + kc * 32),
                                               b[(w * 16 + kc) * 64 + lane], e, 0, 0, 0);
    o = __builtin_amdgcn_mfma_f32_16x16x32_f16(*(const h8v*)(arow + (kc + 1) * 32),
                                               b[(w * 16 + kc + 1) * 64 + lane], o, 0, 0, 0);
  }
  return e + o;
}

__device__ __forceinline__ f4v mm_reg(const _Float16* __restrict__ ACT,
                                      const h8v* __restrict__ reg, int lane) {
  f4v e = {0,0,0,0}, o = {0,0,0,0};
  const _Float16* arow = ACT + (lane & 15) * LD_ + (lane >> 4) * 8;
#pragma unroll
  for (int kc = 0; kc < 16; kc += 2) {
    e = __builtin_amdgcn_mfma_f32_16x16x32_f16(*(const h8v*)(arow + kc * 32),
                                               reg[kc], e, 0, 0, 0);
    o = __builtin_amdgcn_mfma_f32_16x16x32_f16(*(const h8v*)(arow + (kc + 1) * 32),
                                               reg[kc + 1], o, 0, 0, 0);
  }
  return e + o;
}

__launch_bounds__(256, 1)
__global__ void recur(const float* __restrict__ x,
                      const float* __restrict__ tin,
                      const float* __restrict__ bih,
                      const float* __restrict__ bhh,
                      const float* __restrict__ b1g,
                      const float* __restrict__ b2g,
                      const _Float16* __restrict__ Wtil,
                      const _Float16* __restrict__ W1T,
                      const _Float16* __restrict__ W2T,
                      const _Float16* __restrict__ MF,
                      const float* __restrict__ dvec,
                      _Float16* __restrict__ Hsave,
                      ull* __restrict__ Xchg,
                      int* __restrict__ flags) {
  const int blk = blockIdx.x;
  const int j = blk & 7, s = blk >> 3;                      // pair idx, slab
  const int tid = threadIdx.x, w = tid >> 6, lane = tid & 63;
  const int lm = lane & 15, quad = lane >> 4;
  const int col = s * 64 + w * 16 + lm;                     // global hidden col
  const int cidx[2] = {2 * j, 2 * j + 1};

  __shared__ __align__(16) _Float16 W1s[4 * 16 * 512];      // 64 KB
  __shared__ __align__(16) _Float16 ACTs[2][16 * LD_];      // 2 x 16.25 KB

  {
    const h8v* g1 = (const h8v*)(W1T + (size_t)s * 32768);
    h8v* l1 = (h8v*)W1s;
    for (int i = tid; i < 4096; i += 256) l1[i] = g1[i];
  }
  h8v mreg[16], w2reg[16];
  {
    const h8v* gm = (const h8v*)(MF  + ((size_t)(4 * s + w) * 16) * 512);
    const h8v* g2 = (const h8v*)(W2T + ((size_t)(4 * s + w) * 16) * 512);
#pragma unroll
    for (int kc = 0; kc < 16; ++kc) { mreg[kc] = gm[kc * 64 + lane]; w2reg[kc] = g2[kc * 64 + lane]; }
  }
  for (int i = tid; i < 2 * 16 * LD_; i += 256) ACTs[0][i] = (_Float16)0.f;

  const float zb0 = bih[col] + bhh[col];
  const float zb1 = bih[512 + col] + bhh[512 + col];
  const float zb2 = bih[1024 + col] + bhh[1024 + col];
  const float zb3 = bih[1536 + col] + bhh[1536 + col];
  const float b1r = b1g[col], dvr = dvec[col], b2r = b2g[col];

  float cS[2][4] = {{0,0,0,0},{0,0,0,0}}, hS[2][4] = {{0,0,0,0},{0,0,0,0}};
  float u1S[2][4], SSS[2][4], SMS[2][4], dtS[2][4];
  int* cnts[2] = {flags + cidx[0] * 64, flags + cidx[1] * 64};
  unsigned ph = 0;
  __syncthreads();

  for (int ts = 0; ts < T_; ++ts) {
#pragma unroll
    for (int kk = 0; kk < 2; ++kk)
#pragma unroll
      for (int r = 0; r < 4; ++r)
        dtS[kk][r] = tin[(cidx[kk] * 16 + quad * 4 + r) * T_ + ts] * (1.0f / 3.0f);

    // ---- P1: gates z = [h|x]·Wtil^T (K=576; B streamed from L2) ----
#pragma unroll
    for (int kk = 0; kk < 2; ++kk) {
      _Float16* ACT = ACTs[kk];
      gatherX(Xchg, cidx[kk], cnts[kk], ACT, s, tid, ph);
      f4v z0 = {0,0,0,0}, z1 = {0,0,0,0}, z2 = {0,0,0,0}, z3 = {0,0,0,0};
      const _Float16* arow = ACT + lm * LD_ + quad * 8;
      const h8v* wt = (const h8v*)Wtil;
      const int tb = 4 * s + w;
#pragma unroll
      for (int kc = 0; kc < 16; ++kc) {
        h8v av = *(const h8v*)(arow + kc * 32);
        z0 = __builtin_amdgcn_mfma_f32_16x16x32_f16(av, wt[(size_t)((0 * 32 + tb) * 18 + kc) * 64 + lane], z0, 0, 0, 0);
        z1 = __builtin_amdgcn_mfma_f32_16x16x32_f16(av, wt[(size_t)((1 * 32 + tb) * 18 + kc) * 64 + lane], z1, 0, 0, 0);
        z2 = __builtin_amdgcn_mfma_f32_16x16x32_f16(av, wt[(size_t)((2 * 32 + tb) * 18 + kc) * 64 + lane], z2, 0, 0, 0);
        z3 = __builtin_amdgcn_mfma_f32_16x16x32_f16(av, wt[(size_t)((3 * 32 + tb) * 18 + kc) * 64 + lane], z3, 0, 0, 0);
      }
      const float* xr = x + ((size_t)(cidx[kk] * 16 + lm) * T_ + ts) * IN_ + quad * 8;
#pragma unroll
      for (int kx = 0; kx < 2; ++kx) {
        float4 f0 = *(const float4*)(xr + kx * 32);
        float4 f1 = *(const float4*)(xr + kx * 32 + 4);
        h8v av;
        av[0] = (_Float16)f0.x; av[1] = (_Float16)f0.y; av[2] = (_Float16)f0.z; av[3] = (_Float16)f0.w;
        av[4] = (_Float16)f1.x; av[5] = (_Float16)f1.y; av[6] = (_Float16)f1.z; av[7] = (_Float16)f1.w;
        int kc = 16 + kx;
        z0 = __builtin_amdgcn_mfma_f32_16x16x32_f16(av, wt[(size_t)((0 * 32 + tb) * 18 + kc) * 64 + lane], z0, 0, 0, 0);
        z1 = __builtin_amdgcn_mfma_f32_16x16x32_f16(av, wt[(size_t)((1 * 32 + tb) * 18 + kc) * 64 + lane], z1, 0, 0, 0);
        z2 = __builtin_amdgcn_mfma_f32_16x16x32_f16(av, wt[(size_t)((2 * 32 + tb) * 18 + kc) * 64 + lane], z2, 0, 0, 0);
        z3 = __builtin_amdgcn_mfma_f32_16x16x32_f16(av, wt[(size_t)((3 * 32 + tb) * 18 + kc) * 64 + lane], z3, 0, 0, 0);
      }
      __syncthreads();                  // all waves done reading ACT (h_prev)
#pragma unroll
      for (int r = 0; r < 4; ++r) {
        float zi = z0[r] + zb0, zf = z1[r] + zb1, zg = z2[r] + zb2, zo = z3[r] + zb3;
        float cv = fsigm(zf) * cS[kk][r] + fsigm(zi) * ftanh(zg);
        cS[kk][r] = cv;
        hS[kk][r] = fsigm(zo) * ftanh(cv);
        ACT[(quad * 4 + r) * LD_ + col] = (_Float16)hS[kk][r];
      }
      publishX(Xchg, cidx[kk], cnts[kk], ACT, s, tid, ph + 1);
    }
    ++ph;

    // ---- P2: u1 = h·W1^T + b1 ----
#pragma unroll
    for (int kk = 0; kk < 2; ++kk) {
      _Float16* ACT = ACTs[kk];
      gatherX(Xchg, cidx[kk], cnts[kk], ACT, s, tid, ph);
      f4v D = mm_lds(ACT, W1s, w, lane);
      __syncthreads();
#pragma unroll
      for (int r = 0; r < 4; ++r) {
        float uv = D[r] + b1r;
        u1S[kk][r] = uv;
        float t1v = ftanh(uv);
        SSS[kk][r] = t1v;
        ACT[(quad * 4 + r) * LD_ + col] = (_Float16)t1v;
      }
      publishX(Xchg, cidx[kk], cnts[kk], ACT, s, tid, ph + 1);
    }
    ++ph;

    // ---- 3 RK4 unfolds in u-space (M in VGPRs) ----
#pragma unroll 1
    for (int uf = 0; uf < 3; ++uf) {
#pragma unroll
      for (int kk = 0; kk < 2; ++kk) {          // s1: D1 = t1·M
        _Float16* ACT = ACTs[kk];
        gatherX(Xchg, cidx[kk], cnts[kk], ACT, s, tid, ph);
        f4v D = mm_reg(ACT, mreg, lane);
        __syncthreads();
#pragma unroll
        for (int r = 0; r < 4; ++r) {
          float Dv = D[r];
          float u2 = u1S[kk][r] + 0.5f * dtS[kk][r] * (Dv + dvr);
          SMS[kk][r] = Dv;
          float t2v = ftanh(u2);
          SSS[kk][r] += 2.0f * t2v;
          ACT[(quad * 4 + r) * LD_ + col] = (_Float16)t2v;
        }
        publishX(Xchg, cidx[kk], cnts[kk], ACT, s, tid, ph + 1);
      }
      ++ph;

#pragma unroll
      for (int kk = 0; kk < 2; ++kk) {          // s2: D2 = t2·M
        _Float16* ACT = ACTs[kk];
        gatherX(Xchg, cidx[kk], cnts[kk], ACT, s, tid, ph);
        f4v D = mm_reg(ACT, mreg, lane);
        __syncthreads();
#pragma unroll
        for (int r = 0; r < 4; ++r) {
          float Dv = D[r];
          float u3 = u1S[kk][r] + 0.5f * dtS[kk][r] * (Dv + dvr);
          SMS[kk][r] += 2.0f * Dv;
          float t3v = ftanh(u3);
          SSS[kk][r] += 2.0f * t3v;
          ACT[(quad * 4 + r) * LD_ + col] = (_Float16)t3v;
        }
        publishX(Xchg, cidx[kk], cnts[kk], ACT, s, tid, ph + 1);
      }
      ++ph;

#pragma unroll
      for (int kk = 0; kk < 2; ++kk) {          // s3: D3 = t3·M
        _Float16* ACT = ACTs[kk];
        gatherX(Xchg, cidx[kk], cnts[kk], ACT, s, tid, ph);
        f4v D = mm_reg(ACT, mreg, lane);
        __syncthreads();
#pragma unroll
        for (int r = 0; r < 4; ++r) {
          float Dv = D[r];
          float u4 = u1S[kk][r] + dtS[kk][r] * (Dv + dvr);
          SMS[kk][r] += 2.0f * Dv;
          float t4v = ftanh(u4);
          SSS[kk][r] += t4v;
          ACT[(quad * 4 + r) * LD_ + col] = (uf < 2) ? (_Float16)t4v : (_Float16)SSS[kk][r];
        }
        publishX(Xchg, cidx[kk], cnts[kk], ACT, s, tid, ph + 1);
      }
      ++ph;

      if (uf < 2) {
#pragma unroll
        for (int kk = 0; kk < 2; ++kk) {        // s4: D4 = t4·M ; u_next
          _Float16* ACT = ACTs[kk];
          gatherX(Xchg, cidx[kk], cnts[kk], ACT, s, tid, ph);
          f4v D = mm_reg(ACT, mreg, lane);
          __syncthreads();
#pragma unroll
          for (int r = 0; r < 4; ++r) {
            float Dv = D[r];
            SMS[kk][r] += Dv;
            float un = u1S[kk][r] + (dtS[kk][r] * (1.0f / 6.0f)) * SMS[kk][r] + dtS[kk][r] * dvr;
            u1S[kk][r] = un;
            float t1v = ftanh(un);
            SSS[kk][r] += t1v;
            ACT[(quad * 4 + r) * LD_ + col] = (_Float16)t1v;
          }
          publishX(Xchg, cidx[kk], cnts[kk], ACT, s, tid, ph + 1);
        }
        ++ph;
      }
    }

    // ---- P_h: h += (dt/6)·(S_tot·W2^T) + 3dt·b2 ; publish h + Hsave ----
#pragma unroll
    for (int kk = 0; kk < 2; ++kk) {
      _Float16* ACT = ACTs[kk];
      gatherX(Xchg, cidx[kk], cnts[kk], ACT, s, tid, ph);
      f4v D = mm_reg(ACT, w2reg, lane);
      __syncthreads();
#pragma unroll
      for (int r = 0; r < 4; ++r) {
        hS[kk][r] += (dtS[kk][r] * (1.0f / 6.0f)) * D[r] + (3.0f * dtS[kk][r]) * b2r;
        _Float16 hv = (_Float16)hS[kk][r];
        ACT[(quad * 4 + r) * LD_ + col] = hv;
        Hsave[((size_t)(ts + 1) * B_ + cidx[kk] * 16 + quad * 4 + r) * H_ + col] = hv;
      }
      publishX(Xchg, cidx[kk], cnts[kk], ACT, s, tid, ph + 1);
    }
    ++ph;
  }
}

// ---------------- final projection: out = h·Wco^T + bprime ----------------
__global__ void final_out(const _Float16* __restrict__ Hsave,
                          const float* __restrict__ Wco,
                          const float* __restrict__ bprime,
                          float* __restrict__ out) {
  __shared__ float wcs[NC_][520];
  int tid = threadIdx.x;
  for (int i = tid; i < NC_ * 512; i += 256) wcs[i >> 9][i & 511] = Wco[i];
  __syncthreads();
  int r0 = blockIdx.x * 64;
  int rl = tid >> 4, cc = tid & 15;
  for (int pass = 0; pass < 4; ++pass) {
    int row = r0 + pass * 16 + rl;        // row = b*T + t
    int b = row >> 7, t = row & 127;
    const _Float16* hrow = Hsave + ((size_t)(t + 1) * B_ + b) * H_;
    if (cc < NC_) {
      float acc = 0.f;
      for (int k8 = 0; k8 < 64; ++k8) {
        h8v hv = *(const h8v*)(hrow + k8 * 8);
#pragma unroll
        for (int j = 0; j < 8; ++j) acc += (float)hv[j] * wcs[cc][k8 * 8 + j];
      }
      out[(size_t)row * NC_ + cc] = acc + bprime[cc];
    }
  }
}

extern "C" void kernel_launch(void* const* d_in, const int* in_sizes, int n_in,
                              void* d_out, int out_size, void* d_ws, size_t ws_size,
                              hipStream_t stream) {
  (void)in_sizes; (void)n_in; (void)out_size; (void)ws_size;
  const float* x   = (const float*)d_in[0];
  const float* tin = (const float*)d_in[1];
  const float* Wih = (const float*)d_in[2];
  const float* Whh = (const float*)d_in[3];
  const float* bih = (const float*)d_in[4];
  const float* bhh = (const float*)d_in[5];
  const float* W1  = (const float*)d_in[6];
  const float* b1  = (const float*)d_in[7];
  const float* W2  = (const float*)d_in[8];
  const float* b2  = (const float*)d_in[9];
  const float* Wo  = (const float*)d_in[10];
  const float* bo  = (const float*)d_in[11];
  const float* Wc  = (const float*)d_in[12];
  const float* bc  = (const float*)d_in[13];

  char* ws = (char*)d_ws;
  size_t off = 0;
  auto alloc = [&](size_t bytes) -> void* {
    void* p = ws + off;
    off = (off + bytes + 1023) & ~(size_t)1023;
    return p;
  };
  _Float16* Wtil  = (_Float16*)alloc((size_t)2304 * 512 * 2);
  _Float16* W1T   = (_Float16*)alloc((size_t)512 * 512 * 2);
  _Float16* W2T   = (_Float16*)alloc((size_t)512 * 512 * 2);
  _Float16* MF    = (_Float16*)alloc((size_t)512 * 512 * 2);
  float*    Mtmp  = (float*)alloc((size_t)512 * 512 * 4);
  float*    dvec  = (float*)alloc(512 * 4);
  float*    WcoF  = (float*)alloc((size_t)NC_ * 512 * 4);
  float*    bprim = (float*)alloc(64);
  _Float16* Hsave = (_Float16*)alloc((size_t)(T_ + 1) * B_ * H_ * 2);
  ull*      Xchg  = (ull*)alloc((size_t)2 * 16 * 2048 * 8);
  int*      flags = (int*)alloc(2048 * 4);

  hipMemsetAsync(flags, 0, 2048 * 4, stream);

  prep_M<<<64, 256, 0, stream>>>(W1, W2, Mtmp);
  prep_small<<<4, 256, 0, stream>>>(W1, b2, Wc, Wo, bo, bc, dvec, WcoF, bprim);
  prep_wtilde<<<576, 256, 0, stream>>>(Whh, Wih, Wtil);
  prep_fragW<<<128, 256, 0, stream>>>(W1, W1T);
  prep_fragW<<<128, 256, 0, stream>>>(W2, W2T);
  prep_fragM<<<128, 256, 0, stream>>>(Mtmp, MF);
  recur<<<64, 256, 0, stream>>>(x, tin, bih, bhh, b1, b2, Wtil, W1T, W2T, MF,
                                dvec, Hsave, Xchg, flags);
  final_out<<<512, 256, 0, stream>>>(Hsave, WcoF, bprim, (float*)d_out);
}